// Round 1
// baseline (143.928 us; speedup 1.0000x reference)
//
#include <hip/hip_runtime.h>
#include <hip/hip_bf16.h>

#define H 1024
#define V 50257
#define L 10

// ---------------- Workspace layout (floats) ----------------
// 0      : concat2[2048]   (embedded | attn_applied)
// 2048   : x[1024]         (post-combine+relu)
// 3072   : gi[3072]
// 6144   : gh[3072]
// 9216   : h_new[1024]
// 10240  : scal[2]  (max, log-sum-exp)
// 10496  : logits[V]
#define WS_CONCAT   0
#define WS_X        2048
#define WS_GI       3072
#define WS_GH       6144
#define WS_HNEW     9216
#define WS_SCAL     10240
#define WS_LOGITS   10496

// 1 block, 256 threads: embedding fetch, attn logits, softmax, attn_applied
__global__ void k_attn(const int* __restrict__ idx,
                       const float* __restrict__ hidden,
                       const float* __restrict__ enc_outs,
                       const float* __restrict__ emb,
                       const float* __restrict__ attn_W,
                       const float* __restrict__ attn_b,
                       float* __restrict__ ws,
                       float* __restrict__ attnw_out) {
    __shared__ float s_red[256];
    __shared__ float s_w[L];
    const int t = threadIdx.x;
    const float* erow = emb + (size_t)idx[0] * H;
    float* embedded     = ws + WS_CONCAT;
    float* attn_applied = ws + WS_CONCAT + H;

    for (int i = t; i < H; i += 256) embedded[i] = erow[i];

    for (int l = 0; l < L; ++l) {
        const float* w = attn_W + l * 2 * H;
        float acc = 0.f;
        for (int i = t; i < 2 * H; i += 256) {
            float v = (i < H) ? erow[i] : hidden[i - H];
            acc += w[i] * v;
        }
        s_red[t] = acc; __syncthreads();
        for (int s = 128; s > 0; s >>= 1) {
            if (t < s) s_red[t] += s_red[t + s];
            __syncthreads();
        }
        if (t == 0) s_w[l] = s_red[0] + attn_b[l];
        __syncthreads();
    }
    if (t == 0) {
        float m = -1e30f;
        for (int l = 0; l < L; ++l) m = fmaxf(m, s_w[l]);
        float s = 0.f;
        for (int l = 0; l < L; ++l) { s_w[l] = expf(s_w[l] - m); s += s_w[l]; }
        float inv = 1.f / s;
        for (int l = 0; l < L; ++l) s_w[l] *= inv;
    }
    __syncthreads();
    if (t < L) attnw_out[t] = s_w[t];

    for (int i = t; i < H; i += 256) {
        float acc = 0.f;
        #pragma unroll
        for (int l = 0; l < L; ++l) acc += s_w[l] * enc_outs[l * H + i];
        attn_applied[i] = acc;
    }
}

// Generic matvec: out[row] = dot(W[row,:], v) + b[row], optional relu.
// 4 rows per block (1 wave64 per row), float4 loads.
template<int C, bool RELU>
__global__ void k_matvec(const float* __restrict__ W,
                         const float* __restrict__ v,
                         const float* __restrict__ b,
                         float* __restrict__ out, int R) {
    const int wave = threadIdx.x >> 6;
    const int lane = threadIdx.x & 63;
    const int row  = blockIdx.x * 4 + wave;
    if (row >= R) return;
    const float4* w4 = (const float4*)(W + (size_t)row * C);
    const float4* v4 = (const float4*)v;
    float acc = 0.f;
    #pragma unroll
    for (int i = lane; i < C / 4; i += 64) {
        float4 a = w4[i], x = v4[i];
        acc += a.x * x.x + a.y * x.y + a.z * x.z + a.w * x.w;
    }
    #pragma unroll
    for (int off = 32; off > 0; off >>= 1) acc += __shfl_down(acc, off);
    if (lane == 0) {
        float r = acc + b[row];
        if (RELU) r = fmaxf(r, 0.f);
        out[row] = r;
    }
}

// GRU gate combine (biases already added in the matvecs)
__global__ void k_gru(const float* __restrict__ gi,
                      const float* __restrict__ gh,
                      const float* __restrict__ h0,
                      float* __restrict__ h_new,
                      float* __restrict__ hout) {
    const int j = blockIdx.x * blockDim.x + threadIdx.x;
    if (j >= H) return;
    float ir = gi[j],         hr = gh[j];
    float iz = gi[H + j],     hz = gh[H + j];
    float in_ = gi[2 * H + j], hn = gh[2 * H + j];
    float r = 1.f / (1.f + expf(-(ir + hr)));
    float z = 1.f / (1.f + expf(-(iz + hz)));
    float n = tanhf(in_ + r * hn);
    float h = (1.f - z) * n + z * h0[j];
    h_new[j] = h;
    hout[j]  = h;
}

// Single-block max + log-sum-exp over logits[V]
__global__ void k_lse(const float* __restrict__ logits, float* __restrict__ scal) {
    __shared__ float s[256];
    const int t = threadIdx.x;
    float m = -1e30f;
    for (int i = t; i < V; i += 256) m = fmaxf(m, logits[i]);
    s[t] = m; __syncthreads();
    for (int k = 128; k > 0; k >>= 1) {
        if (t < k) s[t] = fmaxf(s[t], s[t + k]);
        __syncthreads();
    }
    const float M = s[0]; __syncthreads();
    float acc = 0.f;
    for (int i = t; i < V; i += 256) acc += expf(logits[i] - M);
    s[t] = acc; __syncthreads();
    for (int k = 128; k > 0; k >>= 1) {
        if (t < k) s[t] += s[t + k];
        __syncthreads();
    }
    if (t == 0) { scal[0] = M; scal[1] = logf(s[0]); }
}

__global__ void k_logsoftmax_write(const float* __restrict__ logits,
                                   const float* __restrict__ scal,
                                   float* __restrict__ out) {
    const int i = blockIdx.x * blockDim.x + threadIdx.x;
    if (i >= V) return;
    out[i] = logits[i] - scal[0] - scal[1];
}

extern "C" void kernel_launch(void* const* d_in, const int* in_sizes, int n_in,
                              void* d_out, int out_size, void* d_ws, size_t ws_size,
                              hipStream_t stream) {
    const int*   idx      = (const int*)  d_in[0];
    const float* hidden   = (const float*)d_in[1];
    // d_in[2] encoder_output: unused
    const float* enc_outs = (const float*)d_in[3];
    const float* emb      = (const float*)d_in[4];
    const float* attn_W   = (const float*)d_in[5];
    const float* attn_b   = (const float*)d_in[6];
    const float* comb_W   = (const float*)d_in[7];
    const float* comb_b   = (const float*)d_in[8];
    const float* W_ih     = (const float*)d_in[9];
    const float* W_hh     = (const float*)d_in[10];
    const float* b_ih     = (const float*)d_in[11];
    const float* b_hh     = (const float*)d_in[12];
    const float* out_W    = (const float*)d_in[13];
    const float* out_b    = (const float*)d_in[14];

    float* ws  = (float*)d_ws;
    float* out = (float*)d_out;   // [0,V) log-probs | [V,V+H) h_new | [V+H,+L) attn_w

    // 1. attention (writes concat2 halves + attn weights straight to d_out)
    k_attn<<<1, 256, 0, stream>>>(idx, hidden, enc_outs, emb, attn_W, attn_b,
                                  ws, out + V + H);
    // 2. combine + relu: x = relu(comb_W @ concat2 + comb_b)
    k_matvec<2 * H, true><<<H / 4, 256, 0, stream>>>(
        comb_W, ws + WS_CONCAT, comb_b, ws + WS_X, H);
    // 3. gi = W_ih @ x + b_ih  (3H rows)
    k_matvec<H, false><<<(3 * H) / 4, 256, 0, stream>>>(
        W_ih, ws + WS_X, b_ih, ws + WS_GI, 3 * H);
    // 4. gh = W_hh @ h0 + b_hh (3H rows)
    k_matvec<H, false><<<(3 * H) / 4, 256, 0, stream>>>(
        W_hh, hidden, b_hh, ws + WS_GH, 3 * H);
    // 5. GRU combine -> h_new (ws) + d_out[V..V+H)
    k_gru<<<(H + 255) / 256, 256, 0, stream>>>(
        ws + WS_GI, ws + WS_GH, hidden, ws + WS_HNEW, out + V);
    // 6. logits = out_W @ h_new + out_b  (V rows)  -- the big one
    k_matvec<H, false><<<(V + 3) / 4, 256, 0, stream>>>(
        out_W, ws + WS_HNEW, out_b, ws + WS_LOGITS, V);
    // 7. max + log-sum-exp
    k_lse<<<1, 256, 0, stream>>>(ws + WS_LOGITS, ws + WS_SCAL);
    // 8. final write
    k_logsoftmax_write<<<(V + 255) / 256, 256, 0, stream>>>(
        ws + WS_LOGITS, ws + WS_SCAL, out);
}

// Round 2
// 60.816 us; speedup vs baseline: 2.3666x; 2.3666x over previous
//
#include <hip/hip_runtime.h>
#include <hip/hip_bf16.h>
#include <math.h>

#define H 1024
#define V 50257
#define L 10

// Big-matvec blocking: 4 waves/block, 4 rows/wave -> 16 rows/block
#define OUT_ROWS_PER_BLOCK 16
#define OUT_NBLOCKS ((V + OUT_ROWS_PER_BLOCK - 1) / OUT_ROWS_PER_BLOCK)  // 3142

// ---------------- Workspace layout (floats) ----------------
#define WS_CONCAT   0            // 2048: [embedded | attn_applied]
#define WS_X        2048         // 1024
#define WS_GH       3072         // 3072
#define WS_HNEW     6144         // 1024
#define WS_LOGITS   8192         // V (ends 58449)
#define WS_PAIRS    58880        // 2*OUT_NBLOCKS (m,s) pairs

__device__ __forceinline__ float wave_reduce(float acc) {
    #pragma unroll
    for (int off = 32; off > 0; off >>= 1) acc += __shfl_down(acc, off);
    return acc;
}

// ---------- K1: attention (1 block, 640 threads = 10 waves) ----------
__global__ void k_attn(const int* __restrict__ idx,
                       const float* __restrict__ hidden,
                       const float* __restrict__ enc_outs,
                       const float* __restrict__ emb,
                       const float* __restrict__ attn_W,
                       const float* __restrict__ attn_b,
                       float* __restrict__ ws,
                       float* __restrict__ attnw_out) {
    __shared__ float s_w[16];
    const int t = threadIdx.x;
    const int wave = t >> 6, lane = t & 63;
    const float* erow = emb + (size_t)idx[0] * H;

    // copy embedded into concat[0..H)
    for (int i = t; i < H; i += 640) ws[WS_CONCAT + i] = erow[i];

    // 10 attention logits, one wave each
    if (wave < L) {
        const float4* w4 = (const float4*)(attn_W + (size_t)wave * 2 * H);
        const float4* e4 = (const float4*)erow;
        const float4* h4 = (const float4*)hidden;
        float acc = 0.f;
        #pragma unroll
        for (int i = lane; i < 512; i += 64) {
            float4 a = w4[i];
            float4 x = (i < 256) ? e4[i] : h4[i - 256];
            acc += a.x * x.x + a.y * x.y + a.z * x.z + a.w * x.w;
        }
        acc = wave_reduce(acc);
        if (lane == 0) s_w[wave] = acc + attn_b[wave];
    }
    __syncthreads();
    if (t == 0) {
        float m = -1e30f;
        #pragma unroll
        for (int l = 0; l < L; ++l) m = fmaxf(m, s_w[l]);
        float s = 0.f;
        #pragma unroll
        for (int l = 0; l < L; ++l) { s_w[l] = expf(s_w[l] - m); s += s_w[l]; }
        float inv = 1.f / s;
        #pragma unroll
        for (int l = 0; l < L; ++l) s_w[l] *= inv;
    }
    __syncthreads();
    if (t < L) attnw_out[t] = s_w[t];

    // attn_applied into concat[H..2H)
    for (int i = t; i < H; i += 640) {
        float acc = 0.f;
        #pragma unroll
        for (int l = 0; l < L; ++l) acc += s_w[l] * enc_outs[l * H + i];
        ws[WS_CONCAT + H + i] = acc;
    }
}

// ---------- K2: combine(+relu) and gh in one grid ----------
// blocks [0,256): x = relu(comb_W @ concat + comb_b)   (H rows, C=2H)
// blocks [256,1024): gh = W_hh @ hidden + b_hh         (3H rows, C=H)
__global__ void k_comb_gh(const float* __restrict__ comb_W,
                          const float* __restrict__ comb_b,
                          const float* __restrict__ W_hh,
                          const float* __restrict__ b_hh,
                          const float* __restrict__ hidden,
                          float* __restrict__ ws) {
    const int wave = threadIdx.x >> 6, lane = threadIdx.x & 63;
    if (blockIdx.x < 256) {
        const int row = blockIdx.x * 4 + wave;
        const float4* w4 = (const float4*)(comb_W + (size_t)row * 2 * H);
        const float4* v4 = (const float4*)(ws + WS_CONCAT);
        float acc = 0.f;
        #pragma unroll
        for (int i = lane; i < 512; i += 64) {
            float4 a = w4[i], x = v4[i];
            acc += a.x * x.x + a.y * x.y + a.z * x.z + a.w * x.w;
        }
        acc = wave_reduce(acc);
        if (lane == 0) ws[WS_X + row] = fmaxf(acc + comb_b[row], 0.f);
    } else {
        const int row = (blockIdx.x - 256) * 4 + wave;   // < 3H
        const float4* w4 = (const float4*)(W_hh + (size_t)row * H);
        const float4* v4 = (const float4*)hidden;
        float acc = 0.f;
        #pragma unroll
        for (int i = lane; i < 256; i += 64) {
            float4 a = w4[i], x = v4[i];
            acc += a.x * x.x + a.y * x.y + a.z * x.z + a.w * x.w;
        }
        acc = wave_reduce(acc);
        if (lane == 0) ws[WS_GH + row] = acc + b_hh[row];
    }
}

// ---------- K3: gi (3 dots per hidden unit) + GRU pointwise ----------
// 64 blocks x 1024 threads; wave handles one hidden unit j
__global__ void k_gi_gru(const float* __restrict__ W_ih,
                         const float* __restrict__ b_ih,
                         const float* __restrict__ hidden,
                         float* __restrict__ ws,
                         float* __restrict__ h_out) {
    const int wave = threadIdx.x >> 6, lane = threadIdx.x & 63;
    const int j = blockIdx.x * 16 + wave;        // < H
    const float4* xv = (const float4*)(ws + WS_X);
    const float4* w0 = (const float4*)(W_ih + (size_t)j * H);
    const float4* w1 = (const float4*)(W_ih + (size_t)(H + j) * H);
    const float4* w2 = (const float4*)(W_ih + (size_t)(2 * H + j) * H);
    float a0 = 0.f, a1 = 0.f, a2 = 0.f;
    #pragma unroll
    for (int i = lane; i < 256; i += 64) {
        float4 x = xv[i];
        float4 b;
        b = w0[i]; a0 += b.x * x.x + b.y * x.y + b.z * x.z + b.w * x.w;
        b = w1[i]; a1 += b.x * x.x + b.y * x.y + b.z * x.z + b.w * x.w;
        b = w2[i]; a2 += b.x * x.x + b.y * x.y + b.z * x.z + b.w * x.w;
    }
    a0 = wave_reduce(a0);
    a1 = wave_reduce(a1);
    a2 = wave_reduce(a2);
    if (lane == 0) {
        const float ir = a0 + b_ih[j];
        const float iz = a1 + b_ih[H + j];
        const float in_ = a2 + b_ih[2 * H + j];
        const float hr = ws[WS_GH + j];
        const float hz = ws[WS_GH + H + j];
        const float hn = ws[WS_GH + 2 * H + j];
        const float r = 1.f / (1.f + expf(-(ir + hr)));
        const float z = 1.f / (1.f + expf(-(iz + hz)));
        const float n = tanhf(in_ + r * hn);
        const float h0j = hidden[j];
        const float h = (1.f - z) * n + z * h0j;
        ws[WS_HNEW + j] = h;
        h_out[j] = h;
    }
}

// ---------- K4: logits = out_W @ h_new + out_b, plus per-block LSE pair ----------
__global__ void k_out_mv(const float* __restrict__ out_W,
                         const float* __restrict__ out_b,
                         const float* __restrict__ ws_in,
                         float* __restrict__ logits,
                         float* __restrict__ pairs) {
    __shared__ float sm[4], ss[4];
    const int wave = threadIdx.x >> 6, lane = threadIdx.x & 63;
    const int base = blockIdx.x * OUT_ROWS_PER_BLOCK + wave * 4;
    const float4* v4 = (const float4*)(ws_in + WS_HNEW);
    float vals[4];
    int nvalid = 0;
    #pragma unroll
    for (int k = 0; k < 4; ++k) {
        const int row = base + k;
        if (row >= V) break;
        const float4* w4 = (const float4*)(out_W + (size_t)row * H);
        float acc = 0.f;
        #pragma unroll
        for (int i = lane; i < 256; i += 64) {
            float4 a = w4[i], x = v4[i];
            acc += a.x * x.x + a.y * x.y + a.z * x.z + a.w * x.w;
        }
        acc = wave_reduce(acc);
        if (lane == 0) {
            const float val = acc + out_b[row];
            logits[row] = val;
            vals[nvalid] = val;
        }
        ++nvalid;
    }
    if (lane == 0) {
        float m = -INFINITY, s = 0.f;
        for (int k = 0; k < nvalid; ++k) m = fmaxf(m, vals[k]);
        for (int k = 0; k < nvalid; ++k) s += expf(vals[k] - m);
        sm[wave] = m; ss[wave] = s;
    }
    __syncthreads();
    if (threadIdx.x == 0) {
        float m = -INFINITY, s = 0.f;
        #pragma unroll
        for (int w = 0; w < 4; ++w) {
            const float pm = sm[w], psv = ss[w];
            if (pm == -INFINITY) continue;
            if (m == -INFINITY) { m = pm; s = psv; }
            else if (pm <= m)   { s += psv * expf(pm - m); }
            else                { s = s * expf(m - pm) + psv; m = pm; }
        }
        pairs[2 * blockIdx.x]     = m;
        pairs[2 * blockIdx.x + 1] = s;
    }
}

// ---------- K5: merge pairs (per-block, redundant) + write log-softmax ----------
__global__ void k_write(const float* __restrict__ logits,
                        const float* __restrict__ pairs,
                        float* __restrict__ out) {
    __shared__ float sm[256], ss[256];
    const int t = threadIdx.x;
    float m = -INFINITY, s = 0.f;
    for (int i = t; i < OUT_NBLOCKS; i += 256) {
        const float pm = pairs[2 * i], psv = pairs[2 * i + 1];
        if (pm == -INFINITY) continue;
        if (m == -INFINITY) { m = pm; s = psv; }
        else if (pm <= m)   { s += psv * expf(pm - m); }
        else                { s = s * expf(m - pm) + psv; m = pm; }
    }
    sm[t] = m; ss[t] = s; __syncthreads();
    for (int k = 128; k > 0; k >>= 1) {
        if (t < k) {
            const float pm = sm[t + k], psv = ss[t + k];
            float cm = sm[t], cs = ss[t];
            if (pm != -INFINITY) {
                if (cm == -INFINITY) { cm = pm; cs = psv; }
                else if (pm <= cm)   { cs += psv * expf(pm - cm); }
                else                 { cs = cs * expf(cm - pm) + psv; cm = pm; }
            }
            sm[t] = cm; ss[t] = cs;
        }
        __syncthreads();
    }
    const float M = sm[0];
    const float LS = logf(ss[0]);
    const int i = blockIdx.x * 256 + t;
    if (i < V) out[i] = logits[i] - M - LS;
}

extern "C" void kernel_launch(void* const* d_in, const int* in_sizes, int n_in,
                              void* d_out, int out_size, void* d_ws, size_t ws_size,
                              hipStream_t stream) {
    const int*   idx      = (const int*)  d_in[0];
    const float* hidden   = (const float*)d_in[1];
    const float* enc_outs = (const float*)d_in[3];
    const float* emb      = (const float*)d_in[4];
    const float* attn_W   = (const float*)d_in[5];
    const float* attn_b   = (const float*)d_in[6];
    const float* comb_W   = (const float*)d_in[7];
    const float* comb_b   = (const float*)d_in[8];
    const float* W_ih     = (const float*)d_in[9];
    const float* W_hh     = (const float*)d_in[10];
    const float* b_ih     = (const float*)d_in[11];
    const float* b_hh     = (const float*)d_in[12];
    const float* out_W    = (const float*)d_in[13];
    const float* out_b    = (const float*)d_in[14];

    float* ws  = (float*)d_ws;
    float* out = (float*)d_out;   // [0,V) log-probs | [V,V+H) h_new | [V+H,+L) attn_w

    // 1. attention -> concat halves in ws, attn weights to out tail
    k_attn<<<1, 640, 0, stream>>>(idx, hidden, enc_outs, emb, attn_W, attn_b,
                                  ws, out + V + H);
    // 2. combine+relu (256 blocks) || gh (768 blocks)
    k_comb_gh<<<1024, 256, 0, stream>>>(comb_W, comb_b, W_hh, b_hh, hidden, ws);
    // 3. gi + GRU pointwise -> h_new in ws and out[V..V+H)
    k_gi_gru<<<64, 1024, 0, stream>>>(W_ih, b_ih, hidden, ws, out + V);
    // 4. big matvec + per-block online-LSE pairs
    k_out_mv<<<OUT_NBLOCKS, 256, 0, stream>>>(out_W, out_b, ws,
                                              ws + WS_LOGITS, ws + WS_PAIRS);
    // 5. merge pairs + write log-softmax
    k_write<<<(V + 255) / 256, 256, 0, stream>>>(ws + WS_LOGITS, ws + WS_PAIRS, out);
}